// Round 1
// baseline (544.992 us; speedup 1.0000x reference)
//
#include <hip/hip_runtime.h>
#include <cfloat>
#include <cstdint>

#define N_GT 20000
#define N_T 50
#define NPA 8000          // N_POS * ALPHA
#define N_POS 2000
#define NT_PAD 52         // 50 padded to multiple of 4 for float4 LDS reads
#define TG 128            // g-tile staged in LDS for the GEMM
#define FB 512            // fitness kernel block size
#define NE 40             // elements per thread in fitness kernel (512*40 >= 20000)

// ---------------- block reduction helpers ----------------
__device__ __forceinline__ float wave_sum(float v) {
#pragma unroll
    for (int o = 32; o > 0; o >>= 1) v += __shfl_down(v, o, 64);
    return v;
}
__device__ __forceinline__ float wave_max(float v) {
#pragma unroll
    for (int o = 32; o > 0; o >>= 1) v = fmaxf(v, __shfl_down(v, o, 64));
    return v;
}
__device__ float block_sum(float v, float* red) {
    int lane = threadIdx.x & 63, wid = threadIdx.x >> 6, nw = blockDim.x >> 6;
    v = wave_sum(v);
    __syncthreads();                  // protect red[] reuse across calls
    if (lane == 0) red[wid] = v;
    __syncthreads();
    if (wid == 0) {
        float x = (lane < nw) ? red[lane] : 0.f;
        x = wave_sum(x);
        if (lane == 0) red[0] = x;
    }
    __syncthreads();
    return red[0];
}
__device__ float block_max(float v, float* red) {
    int lane = threadIdx.x & 63, wid = threadIdx.x >> 6, nw = blockDim.x >> 6;
    v = wave_max(v);
    __syncthreads();
    if (lane == 0) red[wid] = v;
    __syncthreads();
    if (wid == 0) {
        float x = (lane < nw) ? red[lane] : -FLT_MAX;
        x = wave_max(x);
        if (lane == 0) red[0] = x;
    }
    __syncthreads();
    return red[0];
}

// ---------------- softmax + skew loss ----------------
// one block per row t; writes fqm (row-major) and fqmT (transposed, padded to 52)
__global__ __launch_bounds__(256) void softmax_skew_kernel(
    const float* __restrict__ fq, float* __restrict__ fqm,
    float* __restrict__ fqmT, float* __restrict__ out) {
    __shared__ float red[8];
    int t = blockIdx.x;
    const float* row = fq + (size_t)t * N_GT;

    float mx = -FLT_MAX;
    for (int g = threadIdx.x; g < N_GT; g += 256) mx = fmaxf(mx, row[g]);
    mx = block_max(mx, red);

    float s = 0.f;
    for (int g = threadIdx.x; g < N_GT; g += 256) s += expf(row[g] - mx);
    s = block_sum(s, red);
    float inv = 1.f / s;

    float skew = 0.f;
    const float mean = 1.f / (float)N_GT;   // softmax row mean == 1/N_GT
    for (int g = threadIdx.x; g < N_GT; g += 256) {
        float y = expf(row[g] - mx) * inv;
        fqm[(size_t)t * N_GT + g] = y;
        fqmT[(size_t)g * NT_PAD + t] = y;
        if (t == 0) {                        // zero the pad columns once
            fqmT[(size_t)g * NT_PAD + 50] = 0.f;
            fqmT[(size_t)g * NT_PAD + 51] = 0.f;
        }
        float d = y - mean;
        skew += d * d * d;
    }
    skew = block_sum(skew, red);
    // fq_sparsity_loss = -sum_t (skew_t / N_GT) / N_T
    if (threadIdx.x == 0)
        atomicAdd(out + 400001, skew * (-1.f / ((float)N_GT * (float)N_T)));
}

// ---------------- fitness (replicator + KL) loss ----------------
// one block per time-pair t (0..48); per-thread register arrays, 7 block reductions
__global__ __launch_bounds__(FB) void fitness_kernel(
    const float* __restrict__ fqm, const float* __restrict__ fitness,
    float* __restrict__ out) {
    __shared__ float red[8];
    int t = blockIdx.x;
    const float* p0 = fqm + (size_t)t * N_GT;
    const float* p1 = p0 + N_GT;

    float pf[NE], ips[NE], p1m[NE];
    float wsum = 0.f;
#pragma unroll
    for (int j = 0; j < NE; ++j) {
        int g = threadIdx.x + j * FB;
        bool in = g < N_GT;
        float a = in ? p0[g] : 0.f;
        float b = in ? p1[g] : 0.f;
        bool m = in && (a >= 1e-6f);
        float a_m = m ? a : 0.f;
        float b_m = m ? b : 0.f;
        pf[j] = m ? expf(fitness[g]) : 0.f;
        ips[j] = a_m;
        p1m[j] = b_m;
        wsum += b_m;
    }
    float weight = block_sum(wsum, red);

#pragma unroll 1
    for (int it = 0; it < 5; ++it) {
        float sm = 0.f;
#pragma unroll
        for (int j = 0; j < NE; ++j) sm += ips[j] * pf[j];
        float mpf = block_sum(sm, red);
        float r = 1.f / mpf;
#pragma unroll
        for (int j = 0; j < NE; ++j) ips[j] *= pf[j] * r;
    }

    float invw = 1.f / weight;
    float kls = 0.f;
#pragma unroll
    for (int j = 0; j < NE; ++j) {
        float np1 = p1m[j] * invw;
        if (np1 > 0.f) kls += np1 * (logf(np1) - logf(ips[j]));
    }
    float kl = block_sum(kls, red);
    if (threadIdx.x == 0 && weight >= 0.3f)
        atomicAdd(out + 400000, weight * kl * (1.f / (float)(N_T - 1)));
}

// ---------------- GEMM: partial[s][t][p] = sum_{g in slice s} fqm[t][g]*B[g][p] ----------------
__global__ __launch_bounds__(256) void gemm_kernel(
    const float* __restrict__ B, const float* __restrict__ fqmT,
    float* __restrict__ partial, int kchunk) {
    __shared__ __align__(16) float fs[TG][NT_PAD];
    int p = blockIdx.x * 256 + threadIdx.x;
    int s = blockIdx.y;
    int g0 = s * kchunk;
    int g1 = g0 + kchunk; if (g1 > N_GT) g1 = N_GT;
    float acc[NT_PAD];
#pragma unroll
    for (int t = 0; t < NT_PAD; ++t) acc[t] = 0.f;
    bool act = p < NPA;
    const float* Bp = B + p;

    for (int gt = g0; gt < g1; gt += TG) {
        int tg = g1 - gt; if (tg > TG) tg = TG;
        __syncthreads();
        {   // stage fqmT tile (tg x 52) into LDS, float4-coalesced
            const float4* src = reinterpret_cast<const float4*>(fqmT + (size_t)gt * NT_PAD);
            float4* dst = reinterpret_cast<float4*>(&fs[0][0]);
            int n4 = tg * (NT_PAD / 4);
            for (int i = threadIdx.x; i < n4; i += 256) dst[i] = src[i];
        }
        __syncthreads();
        if (act) {
            const float* bcol = Bp + (size_t)gt * NPA;
            if (tg == TG) {
#pragma unroll 2
                for (int j = 0; j < TG; ++j) {
                    float b = bcol[(size_t)j * NPA];
#pragma unroll
                    for (int q = 0; q < NT_PAD / 4; ++q) {
                        float4 f = *reinterpret_cast<const float4*>(&fs[j][q * 4]);
                        acc[q * 4 + 0] = fmaf(f.x, b, acc[q * 4 + 0]);
                        acc[q * 4 + 1] = fmaf(f.y, b, acc[q * 4 + 1]);
                        acc[q * 4 + 2] = fmaf(f.z, b, acc[q * 4 + 2]);
                        acc[q * 4 + 3] = fmaf(f.w, b, acc[q * 4 + 3]);
                    }
                }
            } else {
                for (int j = 0; j < tg; ++j) {
                    float b = bcol[(size_t)j * NPA];
#pragma unroll
                    for (int q = 0; q < NT_PAD / 4; ++q) {
                        float4 f = *reinterpret_cast<const float4*>(&fs[j][q * 4]);
                        acc[q * 4 + 0] = fmaf(f.x, b, acc[q * 4 + 0]);
                        acc[q * 4 + 1] = fmaf(f.y, b, acc[q * 4 + 1]);
                        acc[q * 4 + 2] = fmaf(f.z, b, acc[q * 4 + 2]);
                        acc[q * 4 + 3] = fmaf(f.w, b, acc[q * 4 + 3]);
                    }
                }
            }
        }
    }
    if (act) {
        float* dst = partial + (size_t)s * (N_T * NPA) + p;
#pragma unroll
        for (int t = 0; t < N_T; ++t) dst[(size_t)t * NPA] = acc[t];
    }
}

// ---------------- reduce partials + log ----------------
__global__ __launch_bounds__(256) void reduce_log_kernel(
    const float* __restrict__ partial, float* __restrict__ out, int ns) {
    int i = blockIdx.x * 256 + threadIdx.x;
    if (i >= N_T * NPA) return;
    float s = 0.f;
    for (int k = 0; k < ns; ++k) s += partial[(size_t)k * (N_T * NPA) + i];
    out[i] = logf(s * (1.f / (float)N_POS) + 1e-10f);
}

extern "C" void kernel_launch(void* const* d_in, const int* in_sizes, int n_in,
                              void* d_out, int out_size, void* d_ws, size_t ws_size,
                              hipStream_t stream) {
    const float* fitness = (const float*)d_in[0];
    const float* fq_mat  = (const float*)d_in[1];
    const float* geno    = (const float*)d_in[2];
    float* out = (float*)d_out;

    char* ws = (char*)d_ws;
    float* fqmT   = (float*)ws;                    // 20000*52*4   = 4,160,000 B
    float* fqm    = (float*)(ws + 4160000);        // 50*20000*4   = 4,000,000 B
    float* partial = (float*)(ws + 8160000);       // ns*400000*4

    int ns = 16;
    while (ns > 1 && (size_t)8160000 + (size_t)ns * 1600000 > ws_size) ns >>= 1;
    int kchunk = (N_GT + ns - 1) / ns;

    // zero the two scalar-loss outputs (accumulated via atomics)
    hipMemsetAsync((char*)d_out + (size_t)400000 * sizeof(float), 0, 2 * sizeof(float), stream);

    hipLaunchKernelGGL(softmax_skew_kernel, dim3(N_T), dim3(256), 0, stream,
                       fq_mat, fqm, fqmT, out);
    hipLaunchKernelGGL(fitness_kernel, dim3(N_T - 1), dim3(FB), 0, stream,
                       fqm, fitness, out);
    hipLaunchKernelGGL(gemm_kernel, dim3((NPA + 255) / 256, ns), dim3(256), 0, stream,
                       geno, fqmT, partial, kchunk);
    hipLaunchKernelGGL(reduce_log_kernel, dim3((N_T * NPA + 255) / 256), dim3(256), 0, stream,
                       partial, out, ns);
}

// Round 2
// 443.975 us; speedup vs baseline: 1.2275x; 1.2275x over previous
//
#include <hip/hip_runtime.h>
#include <cfloat>
#include <cstdint>

#define N_GT 20000
#define N_T 50
#define NPA 8000          // N_POS * ALPHA
#define N_POS 2000
#define NT_PAD 52         // 50 padded to multiple of 4 for float4 LDS reads
#define TG 64             // g-tile staged in LDS for the GEMM
#define PB 512            // p-columns per block (256 threads x 2)
#define FB 512            // fitness kernel block size
#define NE 40             // elements per thread in fitness kernel (512*40 >= 20000)

// ---------------- block reduction helpers ----------------
__device__ __forceinline__ float wave_sum(float v) {
#pragma unroll
    for (int o = 32; o > 0; o >>= 1) v += __shfl_down(v, o, 64);
    return v;
}
__device__ __forceinline__ float wave_max(float v) {
#pragma unroll
    for (int o = 32; o > 0; o >>= 1) v = fmaxf(v, __shfl_down(v, o, 64));
    return v;
}
__device__ float block_sum(float v, float* red) {
    int lane = threadIdx.x & 63, wid = threadIdx.x >> 6, nw = blockDim.x >> 6;
    v = wave_sum(v);
    __syncthreads();
    if (lane == 0) red[wid] = v;
    __syncthreads();
    if (wid == 0) {
        float x = (lane < nw) ? red[lane] : 0.f;
        x = wave_sum(x);
        if (lane == 0) red[0] = x;
    }
    __syncthreads();
    return red[0];
}
__device__ float block_max(float v, float* red) {
    int lane = threadIdx.x & 63, wid = threadIdx.x >> 6, nw = blockDim.x >> 6;
    v = wave_max(v);
    __syncthreads();
    if (lane == 0) red[wid] = v;
    __syncthreads();
    if (wid == 0) {
        float x = (lane < nw) ? red[lane] : -FLT_MAX;
        x = wave_max(x);
        if (lane == 0) red[0] = x;
    }
    __syncthreads();
    return red[0];
}

// ---------------- softmax + skew loss ----------------
__global__ __launch_bounds__(256) void softmax_skew_kernel(
    const float* __restrict__ fq, float* __restrict__ fqm,
    float* __restrict__ fqmT, float* __restrict__ out) {
    __shared__ float red[8];
    int t = blockIdx.x;
    const float* row = fq + (size_t)t * N_GT;

    float mx = -FLT_MAX;
    for (int g = threadIdx.x; g < N_GT; g += 256) mx = fmaxf(mx, row[g]);
    mx = block_max(mx, red);

    float s = 0.f;
    for (int g = threadIdx.x; g < N_GT; g += 256) s += expf(row[g] - mx);
    s = block_sum(s, red);
    float inv = 1.f / s;

    float skew = 0.f;
    const float mean = 1.f / (float)N_GT;
    for (int g = threadIdx.x; g < N_GT; g += 256) {
        float y = expf(row[g] - mx) * inv;
        fqm[(size_t)t * N_GT + g] = y;
        fqmT[(size_t)g * NT_PAD + t] = y;
        if (t == 0) {
            fqmT[(size_t)g * NT_PAD + 50] = 0.f;
            fqmT[(size_t)g * NT_PAD + 51] = 0.f;
        }
        float d = y - mean;
        skew += d * d * d;
    }
    skew = block_sum(skew, red);
    if (threadIdx.x == 0)
        atomicAdd(out + 400001, skew * (-1.f / ((float)N_GT * (float)N_T)));
}

// ---------------- fitness (replicator + KL) loss ----------------
__global__ __launch_bounds__(FB) void fitness_kernel(
    const float* __restrict__ fqm, const float* __restrict__ fitness,
    float* __restrict__ out) {
    __shared__ float red[8];
    int t = blockIdx.x;
    const float* p0 = fqm + (size_t)t * N_GT;
    const float* p1 = p0 + N_GT;

    float pf[NE], ips[NE], p1m[NE];
    float wsum = 0.f;
#pragma unroll
    for (int j = 0; j < NE; ++j) {
        int g = threadIdx.x + j * FB;
        bool in = g < N_GT;
        float a = in ? p0[g] : 0.f;
        float b = in ? p1[g] : 0.f;
        bool m = in && (a >= 1e-6f);
        float a_m = m ? a : 0.f;
        float b_m = m ? b : 0.f;
        pf[j] = m ? expf(fitness[g]) : 0.f;
        ips[j] = a_m;
        p1m[j] = b_m;
        wsum += b_m;
    }
    float weight = block_sum(wsum, red);

#pragma unroll 1
    for (int it = 0; it < 5; ++it) {
        float sm = 0.f;
#pragma unroll
        for (int j = 0; j < NE; ++j) sm += ips[j] * pf[j];
        float mpf = block_sum(sm, red);
        float r = 1.f / mpf;
#pragma unroll
        for (int j = 0; j < NE; ++j) ips[j] *= pf[j] * r;
    }

    float invw = 1.f / weight;
    float kls = 0.f;
#pragma unroll
    for (int j = 0; j < NE; ++j) {
        float np1 = p1m[j] * invw;
        if (np1 > 0.f) kls += np1 * (logf(np1) - logf(ips[j]));
    }
    float kl = block_sum(kls, red);
    if (threadIdx.x == 0 && weight >= 0.3f)
        atomicAdd(out + 400000, weight * kl * (1.f / (float)(N_T - 1)));
}

// ---------------- GEMM: partial[s][t][p] = sum_{g in slice s} fqm[t][g]*B[g][p] ----------------
// 2 p-columns per thread: 104 FMAs per 13 ds_read_b128 -> VALU-bound, not LDS-bound
__global__ __launch_bounds__(256, 3) void gemm_kernel(
    const float* __restrict__ B, const float* __restrict__ fqmT,
    float* __restrict__ partial, int kchunk) {
    __shared__ __align__(16) float fs[TG][NT_PAD];
    int p0 = blockIdx.x * PB + threadIdx.x * 2;
    int s = blockIdx.y;
    int g0 = s * kchunk;
    int g1 = g0 + kchunk; if (g1 > N_GT) g1 = N_GT;
    float acc[NT_PAD][2];
#pragma unroll
    for (int t = 0; t < NT_PAD; ++t) { acc[t][0] = 0.f; acc[t][1] = 0.f; }
    bool act = p0 < NPA;  // NPA even -> p0+1 in range too

    for (int gt = g0; gt < g1; gt += TG) {
        int tg = g1 - gt; if (tg > TG) tg = TG;
        __syncthreads();
        {   // stage fqmT tile (tg x 52) into LDS, float4-coalesced
            const float4* src = reinterpret_cast<const float4*>(fqmT + (size_t)gt * NT_PAD);
            float4* dst = reinterpret_cast<float4*>(&fs[0][0]);
            int n4 = tg * (NT_PAD / 4);
            for (int i = threadIdx.x; i < n4; i += 256) dst[i] = src[i];
        }
        __syncthreads();
        if (act) {
            const float* bp = B + (size_t)gt * NPA + p0;
#pragma unroll 2
            for (int j = 0; j < tg; ++j) {
                float2 b = *reinterpret_cast<const float2*>(bp + (size_t)j * NPA);
#pragma unroll
                for (int q = 0; q < NT_PAD / 4; ++q) {
                    float4 f = *reinterpret_cast<const float4*>(&fs[j][q * 4]);
                    acc[q * 4 + 0][0] = fmaf(f.x, b.x, acc[q * 4 + 0][0]);
                    acc[q * 4 + 0][1] = fmaf(f.x, b.y, acc[q * 4 + 0][1]);
                    acc[q * 4 + 1][0] = fmaf(f.y, b.x, acc[q * 4 + 1][0]);
                    acc[q * 4 + 1][1] = fmaf(f.y, b.y, acc[q * 4 + 1][1]);
                    acc[q * 4 + 2][0] = fmaf(f.z, b.x, acc[q * 4 + 2][0]);
                    acc[q * 4 + 2][1] = fmaf(f.z, b.y, acc[q * 4 + 2][1]);
                    acc[q * 4 + 3][0] = fmaf(f.w, b.x, acc[q * 4 + 3][0]);
                    acc[q * 4 + 3][1] = fmaf(f.w, b.y, acc[q * 4 + 3][1]);
                }
            }
        }
    }
    if (act) {
        float* dstp = partial + (size_t)s * (N_T * NPA) + p0;
#pragma unroll
        for (int t = 0; t < N_T; ++t) {
            dstp[(size_t)t * NPA + 0] = acc[t][0];
            dstp[(size_t)t * NPA + 1] = acc[t][1];
        }
    }
}

// ---------------- reduce partials + log ----------------
__global__ __launch_bounds__(256) void reduce_log_kernel(
    const float* __restrict__ partial, float* __restrict__ out, int ns) {
    int i = blockIdx.x * 256 + threadIdx.x;
    if (i >= N_T * NPA) return;
    float s = 0.f;
    for (int k = 0; k < ns; ++k) s += partial[(size_t)k * (N_T * NPA) + i];
    out[i] = logf(s * (1.f / (float)N_POS) + 1e-10f);
}

extern "C" void kernel_launch(void* const* d_in, const int* in_sizes, int n_in,
                              void* d_out, int out_size, void* d_ws, size_t ws_size,
                              hipStream_t stream) {
    const float* fitness = (const float*)d_in[0];
    const float* fq_mat  = (const float*)d_in[1];
    const float* geno    = (const float*)d_in[2];
    float* out = (float*)d_out;

    char* ws = (char*)d_ws;
    float* fqmT    = (float*)ws;                    // 20000*52*4 = 4,160,000 B
    float* fqm     = (float*)(ws + 4160000);        // 50*20000*4 = 4,000,000 B
    float* partial = (float*)(ws + 8160000);        // ns*400000*4

    // pick the largest split-K factor the workspace allows (more blocks -> occupancy)
    const int cand[] = {64, 48, 32, 16, 8, 4, 2, 1};
    int ns = 1;
    for (int i = 0; i < 8; ++i) {
        if ((size_t)8160000 + (size_t)cand[i] * 1600000 <= ws_size) { ns = cand[i]; break; }
    }
    int kchunk = (N_GT + ns - 1) / ns;

    hipMemsetAsync((char*)d_out + (size_t)400000 * sizeof(float), 0, 2 * sizeof(float), stream);

    hipLaunchKernelGGL(softmax_skew_kernel, dim3(N_T), dim3(256), 0, stream,
                       fq_mat, fqm, fqmT, out);
    hipLaunchKernelGGL(fitness_kernel, dim3(N_T - 1), dim3(FB), 0, stream,
                       fqm, fitness, out);
    hipLaunchKernelGGL(gemm_kernel, dim3((NPA + PB - 1) / PB, ns), dim3(256), 0, stream,
                       geno, fqmT, partial, kchunk);
    hipLaunchKernelGGL(reduce_log_kernel, dim3((N_T * NPA + 255) / 256), dim3(256), 0, stream,
                       partial, out, ns);
}

// Round 3
// 254.597 us; speedup vs baseline: 2.1406x; 1.7438x over previous
//
#include <hip/hip_runtime.h>
#include <cfloat>
#include <cstdint>

#define N_GT 20000
#define N_T 50
#define NPA 8000          // N_POS * ALPHA
#define N_POS 2000
#define KSTEPS 625        // N_GT / 32
#define FB 512            // fitness kernel block size
#define NE 40             // elements per thread in fitness kernel

typedef __attribute__((ext_vector_type(8))) short short8;
typedef __attribute__((ext_vector_type(4))) float f32x4;

// ---------------- block reduction helpers ----------------
__device__ __forceinline__ float wave_sum(float v) {
#pragma unroll
    for (int o = 32; o > 0; o >>= 1) v += __shfl_down(v, o, 64);
    return v;
}
__device__ __forceinline__ float wave_max(float v) {
#pragma unroll
    for (int o = 32; o > 0; o >>= 1) v = fmaxf(v, __shfl_down(v, o, 64));
    return v;
}
__device__ float block_sum(float v, float* red) {
    int lane = threadIdx.x & 63, wid = threadIdx.x >> 6, nw = blockDim.x >> 6;
    v = wave_sum(v);
    __syncthreads();
    if (lane == 0) red[wid] = v;
    __syncthreads();
    if (wid == 0) {
        float x = (lane < nw) ? red[lane] : 0.f;
        x = wave_sum(x);
        if (lane == 0) red[0] = x;
    }
    __syncthreads();
    return red[0];
}
__device__ float block_max(float v, float* red) {
    int lane = threadIdx.x & 63, wid = threadIdx.x >> 6, nw = blockDim.x >> 6;
    v = wave_max(v);
    __syncthreads();
    if (lane == 0) red[wid] = v;
    __syncthreads();
    if (wid == 0) {
        float x = (lane < nw) ? red[lane] : -FLT_MAX;
        x = wave_max(x);
        if (lane == 0) red[0] = x;
    }
    __syncthreads();
    return red[0];
}

// ---------------- softmax + skew loss ----------------
// writes fqm (fp32 row-major, for fitness kernel) and fqmb (bf16 RTN, padded
// rows 50..63 zeroed separately, for the MFMA GEMM A operand)
__global__ __launch_bounds__(256) void softmax_skew_kernel(
    const float* __restrict__ fq, float* __restrict__ fqm,
    unsigned short* __restrict__ fqmb, float* __restrict__ out) {
    __shared__ float red[8];
    int t = blockIdx.x;
    const float* row = fq + (size_t)t * N_GT;

    float mx = -FLT_MAX;
    for (int g = threadIdx.x; g < N_GT; g += 256) mx = fmaxf(mx, row[g]);
    mx = block_max(mx, red);

    float s = 0.f;
    for (int g = threadIdx.x; g < N_GT; g += 256) s += expf(row[g] - mx);
    s = block_sum(s, red);
    float inv = 1.f / s;

    float skew = 0.f;
    const float mean = 1.f / (float)N_GT;
    for (int g = threadIdx.x; g < N_GT; g += 256) {
        float y = expf(row[g] - mx) * inv;
        fqm[(size_t)t * N_GT + g] = y;
        unsigned ub = __float_as_uint(y);           // RTN f32 -> bf16
        fqmb[(size_t)t * N_GT + g] = (unsigned short)((ub + 0x7FFFu + ((ub >> 16) & 1u)) >> 16);
        float d = y - mean;
        skew += d * d * d;
    }
    skew = block_sum(skew, red);
    if (threadIdx.x == 0)
        atomicAdd(out + 400001, skew * (-1.f / ((float)N_GT * (float)N_T)));
}

// ---------------- fitness (replicator + KL) loss ----------------
__global__ __launch_bounds__(FB) void fitness_kernel(
    const float* __restrict__ fqm, const float* __restrict__ fitness,
    float* __restrict__ out) {
    __shared__ float red[8];
    int t = blockIdx.x;
    const float* p0 = fqm + (size_t)t * N_GT;
    const float* p1 = p0 + N_GT;

    float pf[NE], ips[NE], p1m[NE];
    float wsum = 0.f;
#pragma unroll
    for (int j = 0; j < NE; ++j) {
        int g = threadIdx.x + j * FB;
        bool in = g < N_GT;
        float a = in ? p0[g] : 0.f;
        float b = in ? p1[g] : 0.f;
        bool m = in && (a >= 1e-6f);
        float a_m = m ? a : 0.f;
        float b_m = m ? b : 0.f;
        pf[j] = m ? expf(fitness[g]) : 0.f;
        ips[j] = a_m;
        p1m[j] = b_m;
        wsum += b_m;
    }
    float weight = block_sum(wsum, red);

#pragma unroll 1
    for (int it = 0; it < 5; ++it) {
        float sm = 0.f;
#pragma unroll
        for (int j = 0; j < NE; ++j) sm += ips[j] * pf[j];
        float mpf = block_sum(sm, red);
        float r = 1.f / mpf;
#pragma unroll
        for (int j = 0; j < NE; ++j) ips[j] *= pf[j] * r;
    }

    float invw = 1.f / weight;
    float kls = 0.f;
#pragma unroll
    for (int j = 0; j < NE; ++j) {
        float np1 = p1m[j] * invw;
        if (np1 > 0.f) kls += np1 * (logf(np1) - logf(ips[j]));
    }
    float kl = block_sum(kls, red);
    if (threadIdx.x == 0 && weight >= 0.3f)
        atomicAdd(out + 400000, weight * kl * (1.f / (float)(N_T - 1)));
}

// ---------------- MFMA GEMM: partial[s][t][p] = sum_{g in slice s} fqm[t][g]*B[g][p] ----
// No LDS. Each wave: 64 p-cols x 64 padded t-rows = 4 m-tiles x 4 n-tiles of
// mfma_f32_16x16x32_bf16. B fragments loaded straight from global fp32 with the
// fragment lane map (n = lane&15 -> coalesced 64B per quarter-wave), converted
// to bf16 by truncation (geno is exactly 0/1 -> exact). A (fqmb) is L2-hot.
// A and B use the SAME assumed k-map, so any bijective k-permutation is safe;
// only the C/D layout (col=lane&15, row=(lane>>4)*4+reg, HW-verified) matters.
__global__ __launch_bounds__(256, 2) void gemm_mfma_kernel(
    const float* __restrict__ B, const unsigned short* __restrict__ Abf,
    float* __restrict__ partial, int ch) {
    const int l = threadIdx.x & 63;
    const int w = threadIdx.x >> 6;
    const int ln = l & 15;
    const int kq8 = (l >> 4) * 8;
    const int p0 = blockIdx.x * 256 + w * 64;
    const int s = blockIdx.y;

    int pc[4];
#pragma unroll
    for (int nt = 0; nt < 4; ++nt) {
        int p = p0 + nt * 16 + ln;
        pc[nt] = p < NPA ? p : NPA - 1;   // clamp loads; stores guarded below
    }

    f32x4 acc[4][4];
#pragma unroll
    for (int mt = 0; mt < 4; ++mt)
#pragma unroll
        for (int nt = 0; nt < 4; ++nt)
            acc[mt][nt] = (f32x4){0.f, 0.f, 0.f, 0.f};

    const int ks0 = s * ch;
    int ks1 = ks0 + ch; if (ks1 > KSTEPS) ks1 = KSTEPS;
    if (ks0 >= ks1) return;

    float b0[4][8], b1[4][8];
    short8 a0[4], a1[4];

#define LOADSTEP(Bf, Av, KS) do {                                              \
    const int k0_ = (KS) * 32 + kq8;                                           \
    const float* gp_ = B + (size_t)k0_ * NPA;                                  \
    _Pragma("unroll") for (int nt_ = 0; nt_ < 4; ++nt_) {                      \
        _Pragma("unroll") for (int j_ = 0; j_ < 8; ++j_)                       \
            Bf[nt_][j_] = gp_[(size_t)j_ * NPA + pc[nt_]];                     \
    }                                                                          \
    const unsigned short* ap_ = Abf + k0_;                                     \
    _Pragma("unroll") for (int mt_ = 0; mt_ < 4; ++mt_)                        \
        Av[mt_] = *(const short8*)(ap_ + (size_t)(mt_ * 16 + ln) * N_GT);      \
} while (0)

#define COMPSTEP(Bf, Av) do {                                                  \
    _Pragma("unroll") for (int nt_ = 0; nt_ < 4; ++nt_) {                      \
        short8 bb_;                                                            \
        _Pragma("unroll") for (int j_ = 0; j_ < 8; ++j_)                       \
            bb_[j_] = (short)(__float_as_uint(Bf[nt_][j_]) >> 16);             \
        _Pragma("unroll") for (int mt_ = 0; mt_ < 4; ++mt_)                    \
            acc[mt_][nt_] = __builtin_amdgcn_mfma_f32_16x16x32_bf16(           \
                Av[mt_], bb_, acc[mt_][nt_], 0, 0, 0);                         \
    }                                                                          \
} while (0)

    LOADSTEP(b0, a0, ks0);
    int ks = ks0;
    for (; ks < ks1 - 1; ks += 2) {
        LOADSTEP(b1, a1, ks + 1);
        COMPSTEP(b0, a0);
        if (ks + 2 < ks1) LOADSTEP(b0, a0, ks + 2);
        COMPSTEP(b1, a1);
    }
    if ((ks1 - ks0) & 1) COMPSTEP(b0, a0);

#undef LOADSTEP
#undef COMPSTEP

    const int rbase = (l >> 4) * 4;
    float* ps = partial + (size_t)s * (N_T * NPA);
#pragma unroll
    for (int mt = 0; mt < 4; ++mt) {
#pragma unroll
        for (int r = 0; r < 4; ++r) {
            int t = mt * 16 + rbase + r;
            if (t < N_T) {
#pragma unroll
                for (int nt = 0; nt < 4; ++nt) {
                    int p = p0 + nt * 16 + ln;
                    if (p < NPA) ps[(size_t)t * NPA + p] = acc[mt][nt][r];
                }
            }
        }
    }
}

// ---------------- reduce partials + log ----------------
__global__ __launch_bounds__(256) void reduce_log_kernel(
    const float* __restrict__ partial, float* __restrict__ out, int ns) {
    int i = blockIdx.x * 256 + threadIdx.x;
    if (i >= N_T * NPA) return;
    float s = 0.f;
    for (int k = 0; k < ns; ++k) s += partial[(size_t)k * (N_T * NPA) + i];
    out[i] = logf(s * (1.f / (float)N_POS) + 1e-10f);
}

extern "C" void kernel_launch(void* const* d_in, const int* in_sizes, int n_in,
                              void* d_out, int out_size, void* d_ws, size_t ws_size,
                              hipStream_t stream) {
    const float* fitness = (const float*)d_in[0];
    const float* fq_mat  = (const float*)d_in[1];
    const float* geno    = (const float*)d_in[2];
    float* out = (float*)d_out;

    char* ws = (char*)d_ws;
    float* fqm           = (float*)ws;                       // 50*20000*4   = 4,000,000 B
    unsigned short* fqmb = (unsigned short*)(ws + 4000000);  // 64*20000*2   = 2,560,000 B
    float* partial       = (float*)(ws + 6560000);           // ns*50*8000*4

    // split-K factor (workspace permitting; ws is ~GB so ns=16 is the normal path)
    int ns = 16;
    while (ns > 1 && (size_t)6560000 + (size_t)ns * 1600000 > ws_size) ns >>= 1;
    int ch = (KSTEPS + ns - 1) / ns;

    // zero the two scalar-loss outputs + the bf16 A-pad rows 50..63
    hipMemsetAsync((char*)d_out + (size_t)400000 * sizeof(float), 0, 2 * sizeof(float), stream);
    hipMemsetAsync((char*)fqmb + (size_t)N_T * N_GT * sizeof(unsigned short), 0,
                   (size_t)14 * N_GT * sizeof(unsigned short), stream);

    hipLaunchKernelGGL(softmax_skew_kernel, dim3(N_T), dim3(256), 0, stream,
                       fq_mat, fqm, fqmb, out);
    hipLaunchKernelGGL(fitness_kernel, dim3(N_T - 1), dim3(FB), 0, stream,
                       fqm, fitness, out);
    hipLaunchKernelGGL(gemm_mfma_kernel, dim3((NPA + 255) / 256, ns), dim3(256), 0, stream,
                       geno, fqmb, partial, ch);
    hipLaunchKernelGGL(reduce_log_kernel, dim3((N_T * NPA + 255) / 256), dim3(256), 0, stream,
                       partial, out, ns);
}

// Round 4
// 217.583 us; speedup vs baseline: 2.5048x; 1.1701x over previous
//
#include <hip/hip_runtime.h>
#include <cfloat>
#include <cstdint>

#define N_GT 20000
#define N_T 50
#define NPA 8000          // N_POS * ALPHA
#define N_POS 2000
#define KSTEPS 625        // N_GT / 32
#define FB 512            // fitness kernel block size
#define NE 40             // elements per thread in fitness kernel
#define SCH 2500          // softmax chunk (8 chunks per row)

typedef __attribute__((ext_vector_type(8))) short short8;
typedef __attribute__((ext_vector_type(4))) float f32x4;

// ---------------- block reduction helpers ----------------
__device__ __forceinline__ float wave_sum(float v) {
#pragma unroll
    for (int o = 32; o > 0; o >>= 1) v += __shfl_down(v, o, 64);
    return v;
}
__device__ float block_sum(float v, float* red) {
    int lane = threadIdx.x & 63, wid = threadIdx.x >> 6, nw = blockDim.x >> 6;
    v = wave_sum(v);
    __syncthreads();
    if (lane == 0) red[wid] = v;
    __syncthreads();
    if (wid == 0) {
        float x = (lane < nw) ? red[lane] : 0.f;
        x = wave_sum(x);
        if (lane == 0) red[0] = x;
    }
    __syncthreads();
    return red[0];
}

// ---------------- softmax pass 1: per-chunk sum of exp ----------------
__global__ __launch_bounds__(256) void softmax_sum_kernel(
    const float* __restrict__ fq, float* __restrict__ rowsum) {
    __shared__ float red[8];
    int row = blockIdx.x >> 3, c = blockIdx.x & 7;
    const float* p = fq + (size_t)row * N_GT + c * SCH;
    float s = 0.f;
    for (int i = threadIdx.x; i < SCH; i += 256) s += __expf(p[i]);
    s = block_sum(s, red);
    if (threadIdx.x == 0) rowsum[blockIdx.x] = s;
}

// ---------------- softmax pass 2: normalize, write fqm/fqmb, skew ----------------
__global__ __launch_bounds__(256) void softmax_write_kernel(
    const float* __restrict__ fq, const float* __restrict__ rowsum,
    float* __restrict__ fqm, unsigned short* __restrict__ fqmb,
    float* __restrict__ out) {
    __shared__ float red[8];
    int row = blockIdx.x >> 3, c = blockIdx.x & 7;
    float S = 0.f;
#pragma unroll
    for (int j = 0; j < 8; ++j) S += rowsum[row * 8 + j];
    float inv = 1.f / S;

    const float* p = fq + (size_t)row * N_GT + c * SCH;
    float* ym = fqm + (size_t)row * N_GT + c * SCH;
    unsigned short* yb = fqmb + (size_t)row * N_GT + c * SCH;
    const float mean = 1.f / (float)N_GT;
    float skew = 0.f;
    for (int i = threadIdx.x; i < SCH; i += 256) {
        float y = __expf(p[i]) * inv;
        ym[i] = y;
        unsigned ub = __float_as_uint(y);           // RTN f32 -> bf16
        yb[i] = (unsigned short)((ub + 0x7FFFu + ((ub >> 16) & 1u)) >> 16);
        float d = y - mean;
        skew += d * d * d;
    }
    skew = block_sum(skew, red);
    if (threadIdx.x == 0)
        atomicAdd(out + 400001, skew * (-1.f / ((float)N_GT * (float)N_T)));
}

// ---------------- fitness (replicator + KL) loss ----------------
__global__ __launch_bounds__(FB) void fitness_kernel(
    const float* __restrict__ fqm, const float* __restrict__ fitness,
    float* __restrict__ out) {
    __shared__ float red[8];
    int t = blockIdx.x;
    const float* p0 = fqm + (size_t)t * N_GT;
    const float* p1 = p0 + N_GT;

    float pf[NE], ips[NE], p1m[NE];
    float wsum = 0.f;
#pragma unroll
    for (int j = 0; j < NE; ++j) {
        int g = threadIdx.x + j * FB;
        bool in = g < N_GT;
        float a = in ? p0[g] : 0.f;
        float b = in ? p1[g] : 0.f;
        bool m = in && (a >= 1e-6f);
        float a_m = m ? a : 0.f;
        float b_m = m ? b : 0.f;
        pf[j] = m ? __expf(fitness[g]) : 0.f;
        ips[j] = a_m;
        p1m[j] = b_m;
        wsum += b_m;
    }
    float weight = block_sum(wsum, red);

#pragma unroll 1
    for (int it = 0; it < 5; ++it) {
        float sm = 0.f;
#pragma unroll
        for (int j = 0; j < NE; ++j) sm += ips[j] * pf[j];
        float mpf = block_sum(sm, red);
        float r = 1.f / mpf;
#pragma unroll
        for (int j = 0; j < NE; ++j) ips[j] *= pf[j] * r;
    }

    float invw = 1.f / weight;
    float kls = 0.f;
#pragma unroll
    for (int j = 0; j < NE; ++j) {
        float np1 = p1m[j] * invw;
        if (np1 > 0.f) kls += np1 * (__logf(np1) - __logf(ips[j]));
    }
    float kl = block_sum(kls, red);
    if (threadIdx.x == 0 && weight >= 0.3f)
        atomicAdd(out + 400000, weight * kl * (1.f / (float)(N_T - 1)));
}

// ---------------- MFMA GEMM: partial[s][t][p] = sum_{g in slice s} fqm[t][g]*B[g][p] ----
__global__ __launch_bounds__(256, 2) void gemm_mfma_kernel(
    const float* __restrict__ B, const unsigned short* __restrict__ Abf,
    float* __restrict__ partial, int ch) {
    const int l = threadIdx.x & 63;
    const int w = threadIdx.x >> 6;
    const int ln = l & 15;
    const int kq8 = (l >> 4) * 8;
    const int p0 = blockIdx.x * 256 + w * 64;
    const int s = blockIdx.y;

    int pc[4];
#pragma unroll
    for (int nt = 0; nt < 4; ++nt) {
        int p = p0 + nt * 16 + ln;
        pc[nt] = p < NPA ? p : NPA - 1;   // clamp loads; stores guarded below
    }

    f32x4 acc[4][4];
#pragma unroll
    for (int mt = 0; mt < 4; ++mt)
#pragma unroll
        for (int nt = 0; nt < 4; ++nt)
            acc[mt][nt] = (f32x4){0.f, 0.f, 0.f, 0.f};

    const int ks0 = s * ch;
    int ks1 = ks0 + ch; if (ks1 > KSTEPS) ks1 = KSTEPS;
    if (ks0 >= ks1) return;

    float b0[4][8], b1[4][8];
    short8 a0[4], a1[4];

#define LOADSTEP(Bf, Av, KS) do {                                              \
    const int k0_ = (KS) * 32 + kq8;                                           \
    const float* gp_ = B + (size_t)k0_ * NPA;                                  \
    _Pragma("unroll") for (int nt_ = 0; nt_ < 4; ++nt_) {                      \
        _Pragma("unroll") for (int j_ = 0; j_ < 8; ++j_)                       \
            Bf[nt_][j_] = gp_[(size_t)j_ * NPA + pc[nt_]];                     \
    }                                                                          \
    const unsigned short* ap_ = Abf + k0_;                                     \
    _Pragma("unroll") for (int mt_ = 0; mt_ < 4; ++mt_)                        \
        Av[mt_] = *(const short8*)(ap_ + (size_t)(mt_ * 16 + ln) * N_GT);      \
} while (0)

#define COMPSTEP(Bf, Av) do {                                                  \
    _Pragma("unroll") for (int nt_ = 0; nt_ < 4; ++nt_) {                      \
        short8 bb_;                                                            \
        _Pragma("unroll") for (int j_ = 0; j_ < 8; ++j_)                       \
            bb_[j_] = (short)(__float_as_uint(Bf[nt_][j_]) >> 16);             \
        _Pragma("unroll") for (int mt_ = 0; mt_ < 4; ++mt_)                    \
            acc[mt_][nt_] = __builtin_amdgcn_mfma_f32_16x16x32_bf16(           \
                Av[mt_], bb_, acc[mt_][nt_], 0, 0, 0);                         \
    }                                                                          \
} while (0)

    LOADSTEP(b0, a0, ks0);
    int ks = ks0;
    for (; ks < ks1 - 1; ks += 2) {
        LOADSTEP(b1, a1, ks + 1);
        COMPSTEP(b0, a0);
        if (ks + 2 < ks1) LOADSTEP(b0, a0, ks + 2);
        COMPSTEP(b1, a1);
    }
    if ((ks1 - ks0) & 1) COMPSTEP(b0, a0);

#undef LOADSTEP
#undef COMPSTEP

    const int rbase = (l >> 4) * 4;
    float* ps = partial + (size_t)s * (N_T * NPA);
#pragma unroll
    for (int mt = 0; mt < 4; ++mt) {
#pragma unroll
        for (int r = 0; r < 4; ++r) {
            int t = mt * 16 + rbase + r;
            if (t < N_T) {
#pragma unroll
                for (int nt = 0; nt < 4; ++nt) {
                    int p = p0 + nt * 16 + ln;
                    if (p < NPA) ps[(size_t)t * NPA + p] = acc[mt][nt][r];
                }
            }
        }
    }
}

// ---------------- reduce partials + log (float4) ----------------
__global__ __launch_bounds__(256) void reduce_log_kernel(
    const float4* __restrict__ partial, float4* __restrict__ out, int ns) {
    int i = blockIdx.x * 256 + threadIdx.x;
    if (i >= (N_T * NPA) / 4) return;
    float4 s = {0.f, 0.f, 0.f, 0.f};
    for (int k = 0; k < ns; ++k) {
        float4 v = partial[(size_t)k * ((N_T * NPA) / 4) + i];
        s.x += v.x; s.y += v.y; s.z += v.z; s.w += v.w;
    }
    const float r = 1.f / (float)N_POS;
    float4 o;
    o.x = __logf(s.x * r + 1e-10f);
    o.y = __logf(s.y * r + 1e-10f);
    o.z = __logf(s.z * r + 1e-10f);
    o.w = __logf(s.w * r + 1e-10f);
    out[i] = o;
}

extern "C" void kernel_launch(void* const* d_in, const int* in_sizes, int n_in,
                              void* d_out, int out_size, void* d_ws, size_t ws_size,
                              hipStream_t stream) {
    const float* fitness = (const float*)d_in[0];
    const float* fq_mat  = (const float*)d_in[1];
    const float* geno    = (const float*)d_in[2];
    float* out = (float*)d_out;

    char* ws = (char*)d_ws;
    float* fqm           = (float*)ws;                       // 50*20000*4 = 4,000,000 B
    unsigned short* fqmb = (unsigned short*)(ws + 4000000);  // 64*20000*2 = 2,560,000 B
    float* rowsum        = (float*)(ws + 6560000);           // 400*4      = 1,600 B
    float* partial       = (float*)(ws + 6561600);           // ns*50*8000*4

    int ns = 16;
    while (ns > 1 && (size_t)6561600 + (size_t)ns * 1600000 > ws_size) ns >>= 1;
    int ch = (KSTEPS + ns - 1) / ns;

    // zero the two scalar-loss outputs + the bf16 A-pad rows 50..63
    hipMemsetAsync((char*)d_out + (size_t)400000 * sizeof(float), 0, 2 * sizeof(float), stream);
    hipMemsetAsync((char*)fqmb + (size_t)N_T * N_GT * sizeof(unsigned short), 0,
                   (size_t)14 * N_GT * sizeof(unsigned short), stream);

    hipLaunchKernelGGL(softmax_sum_kernel, dim3(N_T * 8), dim3(256), 0, stream,
                       fq_mat, rowsum);
    hipLaunchKernelGGL(softmax_write_kernel, dim3(N_T * 8), dim3(256), 0, stream,
                       fq_mat, rowsum, fqm, fqmb, out);
    hipLaunchKernelGGL(fitness_kernel, dim3(N_T - 1), dim3(FB), 0, stream,
                       fqm, fitness, out);
    hipLaunchKernelGGL(gemm_mfma_kernel, dim3((NPA + 255) / 256, ns), dim3(256), 0, stream,
                       geno, fqmb, partial, ch);
    hipLaunchKernelGGL(reduce_log_kernel, dim3(((N_T * NPA) / 4 + 255) / 256), dim3(256), 0, stream,
                       (const float4*)partial, (float4*)out, ns);
}

// Round 5
// 164.527 us; speedup vs baseline: 3.3125x; 1.3225x over previous
//
#include <hip/hip_runtime.h>
#include <cfloat>
#include <cstdint>

#define N_GT 20000
#define N_T 50
#define NPA 8000          // N_POS * ALPHA
#define N_POS 2000
#define KSTEPS 625        // N_GT / 32
#define KTILE 32          // k rows per LDS tile
#define PBLK 256          // p columns per block
#define FB 512            // fitness kernel block size
#define NE 40             // elements per thread in fitness kernel
#define SCH 2500          // softmax chunk (8 chunks per row)

typedef __attribute__((ext_vector_type(8))) short short8;
typedef __attribute__((ext_vector_type(4))) float f32x4;

// ---------------- block reduction helpers ----------------
__device__ __forceinline__ float wave_sum(float v) {
#pragma unroll
    for (int o = 32; o > 0; o >>= 1) v += __shfl_down(v, o, 64);
    return v;
}
__device__ float block_sum(float v, float* red) {
    int lane = threadIdx.x & 63, wid = threadIdx.x >> 6, nw = blockDim.x >> 6;
    v = wave_sum(v);
    __syncthreads();
    if (lane == 0) red[wid] = v;
    __syncthreads();
    if (wid == 0) {
        float x = (lane < nw) ? red[lane] : 0.f;
        x = wave_sum(x);
        if (lane == 0) red[0] = x;
    }
    __syncthreads();
    return red[0];
}

// ---------------- softmax pass 1: per-chunk sum of exp ----------------
__global__ __launch_bounds__(256) void softmax_sum_kernel(
    const float* __restrict__ fq, float* __restrict__ rowsum) {
    __shared__ float red[8];
    int row = blockIdx.x >> 3, c = blockIdx.x & 7;
    const float* p = fq + (size_t)row * N_GT + c * SCH;
    float s = 0.f;
    for (int i = threadIdx.x; i < SCH; i += 256) s += __expf(p[i]);
    s = block_sum(s, red);
    if (threadIdx.x == 0) rowsum[blockIdx.x] = s;
}

// ---------------- softmax pass 2: normalize, write fqm/fqmb, skew ----------------
__global__ __launch_bounds__(256) void softmax_write_kernel(
    const float* __restrict__ fq, const float* __restrict__ rowsum,
    float* __restrict__ fqm, unsigned short* __restrict__ fqmb,
    float* __restrict__ out) {
    __shared__ float red[8];
    int row = blockIdx.x >> 3, c = blockIdx.x & 7;
    float S = 0.f;
#pragma unroll
    for (int j = 0; j < 8; ++j) S += rowsum[row * 8 + j];
    float inv = 1.f / S;

    const float* p = fq + (size_t)row * N_GT + c * SCH;
    float* ym = fqm + (size_t)row * N_GT + c * SCH;
    unsigned short* yb = fqmb + (size_t)row * N_GT + c * SCH;
    const float mean = 1.f / (float)N_GT;
    float skew = 0.f;
    for (int i = threadIdx.x; i < SCH; i += 256) {
        float y = __expf(p[i]) * inv;
        ym[i] = y;
        unsigned ub = __float_as_uint(y);           // RTN f32 -> bf16
        yb[i] = (unsigned short)((ub + 0x7FFFu + ((ub >> 16) & 1u)) >> 16);
        float d = y - mean;
        skew += d * d * d;
    }
    skew = block_sum(skew, red);
    if (threadIdx.x == 0)
        atomicAdd(out + 400001, skew * (-1.f / ((float)N_GT * (float)N_T)));
}

// ---------------- fitness loss (telescoped replicator + KL) ----------------
// replicator telescopes: ips after 5 steps = p0*e^{5f} / sum(p0*e^{5f})
// -> 3 serial block reductions instead of 7.
__global__ __launch_bounds__(FB) void fitness_kernel(
    const float* __restrict__ fqm, const float* __restrict__ fitness,
    float* __restrict__ out) {
    __shared__ float red[8];
    int t = blockIdx.x;
    const float* p0 = fqm + (size_t)t * N_GT;
    const float* p1 = p0 + N_GT;

    float p0m[NE], p1m[NE], l5f[NE];
    float wsum = 0.f, s5 = 0.f;
#pragma unroll
    for (int j = 0; j < NE; ++j) {
        int g = threadIdx.x + j * FB;
        bool in = g < N_GT;
        float a = in ? p0[g] : 0.f;
        float b = in ? p1[g] : 0.f;
        bool m = in && (a >= 1e-6f);
        p0m[j] = m ? a : 0.f;
        p1m[j] = m ? b : 0.f;
        l5f[j] = in ? 5.f * fitness[g] : 0.f;
        wsum += p1m[j];
        s5 += p0m[j] * __expf(l5f[j]);
    }
    float weight = block_sum(wsum, red);
    float S5 = block_sum(s5, red);
    float lS5 = __logf(S5);
    float invw = 1.f / weight;

    float kls = 0.f;
#pragma unroll
    for (int j = 0; j < NE; ++j) {
        if (p1m[j] > 0.f) {
            float np1 = p1m[j] * invw;
            float lips = __logf(p0m[j]) + l5f[j] - lS5;  // log of final ips
            kls += np1 * (__logf(np1) - lips);
        }
    }
    float kl = block_sum(kls, red);
    if (threadIdx.x == 0 && weight >= 0.3f)
        atomicAdd(out + 400000, weight * kl * (1.f / (float)(N_T - 1)));
}

// ---------------- MFMA GEMM with global_load_lds-staged B ----------------
// partial[s][t][p] = sum_{g in slice s} fqm[t][g] * B[g][p]
// B tile (32k x 256p fp32, 32KB) double-buffered in LDS via async
// global_load_lds dwordx4 (fully coalesced, 64KB in flight per CU).
// Wave w covers p = pblk + w*64 + ln*4 + nt (n-map permuted for float4
// LDS reads + float4 stores; safe since load & store agree).
__global__ __launch_bounds__(256, 2) void gemm_mfma_kernel(
    const float* __restrict__ B, const unsigned short* __restrict__ Abf,
    float* __restrict__ partial, int ch) {
    __shared__ __align__(16) float lds[2][KTILE][PBLK];   // 64 KB
    const int tid = threadIdx.x;
    const int l = tid & 63, w = tid >> 6;
    const int ln = l & 15, kq = l >> 4;
    const int kq8 = kq * 8;
    const int woff = w * 64;                  // wave's p-offset within tile (floats)
    const int pblk = blockIdx.x * PBLK;
    const int s = blockIdx.y;

    const int ks0 = s * ch;
    int ks1 = ks0 + ch; if (ks1 > KSTEPS) ks1 = KSTEPS;
    const int nk = ks1 - ks0;
    if (nk <= 0) return;

    // staging source column for this lane (clamp only matters for last block)
    int scol = pblk + l * 4;
    if (scol > NPA - 4) scol = NPA - 4;

    const unsigned short* abase = Abf + (size_t)ln * N_GT;

    f32x4 acc[4][4];
#pragma unroll
    for (int mt = 0; mt < 4; ++mt)
#pragma unroll
        for (int nt = 0; nt < 4; ++nt)
            acc[mt][nt] = (f32x4){0.f, 0.f, 0.f, 0.f};

    short8 a0[4], a1[4];

#define STAGE(BUF, KS) do {                                                    \
    const float* gsrc_ = B + (size_t)(KS) * (KTILE * NPA) + scol;              \
    _Pragma("unroll") for (int it_ = 0; it_ < 8; ++it_) {                      \
        int row_ = w * 8 + it_;                                                \
        __builtin_amdgcn_global_load_lds(                                      \
            (const __attribute__((address_space(1))) void*)(gsrc_ + (size_t)row_ * NPA), \
            (__attribute__((address_space(3))) void*)&lds[BUF][row_][0],       \
            16, 0, 0);                                                         \
    }                                                                          \
} while (0)

#define LOADA(AV, KS) do {                                                     \
    const int k0_ = (KS) * 32 + kq8;                                           \
    _Pragma("unroll") for (int mt_ = 0; mt_ < 4; ++mt_)                        \
        AV[mt_] = *(const short8*)(abase + (size_t)(mt_ * 16) * N_GT + k0_);   \
} while (0)

#define COMPUTE(BUF, AV) do {                                                  \
    f32x4 f_[8];                                                               \
    _Pragma("unroll") for (int j_ = 0; j_ < 8; ++j_)                           \
        f_[j_] = *(const f32x4*)&lds[BUF][kq8 + j_][woff + ln * 4];            \
    _Pragma("unroll") for (int nt_ = 0; nt_ < 4; ++nt_) {                      \
        short8 bb_;                                                            \
        _Pragma("unroll") for (int j_ = 0; j_ < 8; ++j_)                       \
            bb_[j_] = (short)(__float_as_uint(f_[j_][nt_]) >> 16);             \
        _Pragma("unroll") for (int mt_ = 0; mt_ < 4; ++mt_)                    \
            acc[mt_][nt_] = __builtin_amdgcn_mfma_f32_16x16x32_bf16(           \
                AV[mt_], bb_, acc[mt_][nt_], 0, 0, 0);                         \
    }                                                                          \
} while (0)

    STAGE(0, ks0);
    LOADA(a0, ks0);
    int i = 0;
    for (; i + 1 < nk; i += 2) {
        __syncthreads();                       // tile i staged & prev reads done
        STAGE(1, ks0 + i + 1);
        LOADA(a1, ks0 + i + 1);
        COMPUTE(0, a0);
        __syncthreads();                       // tile i+1 staged & reads of buf0 done
        if (i + 2 < nk) { STAGE(0, ks0 + i + 2); LOADA(a0, ks0 + i + 2); }
        COMPUTE(1, a1);
    }
    if (i < nk) {                              // odd tail (tile in buf 0)
        __syncthreads();
        COMPUTE(0, a0);
    }

#undef STAGE
#undef LOADA
#undef COMPUTE

    // epilogue: lane holds cols pwave + ln*4 + {0,1,2,3} -> float4 stores
    const int rbase = kq * 4;
    const int pst = pblk + woff + ln * 4;
    float* ps = partial + (size_t)s * (N_T * NPA);
    if (pst < NPA) {
#pragma unroll
        for (int mt = 0; mt < 4; ++mt) {
#pragma unroll
            for (int r = 0; r < 4; ++r) {
                int t = mt * 16 + rbase + r;
                if (t < N_T) {
                    float4 v = {acc[mt][0][r], acc[mt][1][r],
                                acc[mt][2][r], acc[mt][3][r]};
                    *reinterpret_cast<float4*>(ps + (size_t)t * NPA + pst) = v;
                }
            }
        }
    }
}

// ---------------- reduce partials + log (float4) ----------------
__global__ __launch_bounds__(256) void reduce_log_kernel(
    const float4* __restrict__ partial, float4* __restrict__ out, int ns) {
    int i = blockIdx.x * 256 + threadIdx.x;
    if (i >= (N_T * NPA) / 4) return;
    float4 s = {0.f, 0.f, 0.f, 0.f};
    for (int k = 0; k < ns; ++k) {
        float4 v = partial[(size_t)k * ((N_T * NPA) / 4) + i];
        s.x += v.x; s.y += v.y; s.z += v.z; s.w += v.w;
    }
    const float r = 1.f / (float)N_POS;
    float4 o;
    o.x = __logf(s.x * r + 1e-10f);
    o.y = __logf(s.y * r + 1e-10f);
    o.z = __logf(s.z * r + 1e-10f);
    o.w = __logf(s.w * r + 1e-10f);
    out[i] = o;
}

extern "C" void kernel_launch(void* const* d_in, const int* in_sizes, int n_in,
                              void* d_out, int out_size, void* d_ws, size_t ws_size,
                              hipStream_t stream) {
    const float* fitness = (const float*)d_in[0];
    const float* fq_mat  = (const float*)d_in[1];
    const float* geno    = (const float*)d_in[2];
    float* out = (float*)d_out;

    char* ws = (char*)d_ws;
    float* fqm           = (float*)ws;                       // 50*20000*4 = 4,000,000 B
    unsigned short* fqmb = (unsigned short*)(ws + 4000000);  // 64*20000*2 = 2,560,000 B
    float* rowsum        = (float*)(ws + 6560000);           // 400*4      = 1,600 B
    float* partial       = (float*)(ws + 6561600);           // ns*50*8000*4

    int ns = 16;
    while (ns > 1 && (size_t)6561600 + (size_t)ns * 1600000 > ws_size) ns >>= 1;
    int ch = (KSTEPS + ns - 1) / ns;

    // zero the two scalar-loss outputs + the bf16 A-pad rows 50..63
    hipMemsetAsync((char*)d_out + (size_t)400000 * sizeof(float), 0, 2 * sizeof(float), stream);
    hipMemsetAsync((char*)fqmb + (size_t)N_T * N_GT * sizeof(unsigned short), 0,
                   (size_t)14 * N_GT * sizeof(unsigned short), stream);

    hipLaunchKernelGGL(softmax_sum_kernel, dim3(N_T * 8), dim3(256), 0, stream,
                       fq_mat, rowsum);
    hipLaunchKernelGGL(softmax_write_kernel, dim3(N_T * 8), dim3(256), 0, stream,
                       fq_mat, rowsum, fqm, fqmb, out);
    hipLaunchKernelGGL(fitness_kernel, dim3(N_T - 1), dim3(FB), 0, stream,
                       fqm, fitness, out);
    hipLaunchKernelGGL(gemm_mfma_kernel, dim3(NPA / PBLK + 1, ns), dim3(256), 0, stream,
                       geno, fqmb, partial, ch);
    hipLaunchKernelGGL(reduce_log_kernel, dim3(((N_T * NPA) / 4 + 255) / 256), dim3(256), 0, stream,
                       (const float4*)partial, (float4*)out, ns);
}